// Round 1
// baseline (1244.554 us; speedup 1.0000x reference)
//
#include <hip/hip_runtime.h>

// RNNLM: logits[T,B,V] = (scan_t sigmoid(h@H + emb[x]@I + b1)) @ U + b2 ; plus final h.
// V=32000 E=1024 Hd=1024 T=64 B=32.
// Strategy: fp16 MFMA GEMMs (no fp32 MFMA on CDNA4; fp16 keeps ~5e-4 rel err),
// batch-parallel recurrence (32 independent chains, no grid sync), one-time
// transpose/convert of U and I into workspace so both GEMM operands are
// K-contiguous for ds_read_b128 fragment loads.

typedef _Float16 f16;
typedef f16 f16x2 __attribute__((ext_vector_type(2)));
typedef f16 f16x4 __attribute__((ext_vector_type(4)));
typedef f16 f16x8 __attribute__((ext_vector_type(8)));
typedef float f32x4 __attribute__((ext_vector_type(4)));

static constexpr int Vv = 32000, Ee = 1024, Hd = 1024, Tt = 64, Bb = 32;
static constexpr int Mm = Tt * Bb; // 2048 rows (t*B+b)

// async global->LDS, 16B per lane; LDS dest = wave-uniform base + lane*16
#define GLOAD16(g, l)                                                          \
  __builtin_amdgcn_global_load_lds(                                            \
      (const __attribute__((address_space(1))) void*)(g),                      \
      (__attribute__((address_space(3))) void*)(l), 16, 0, 0)

// ---------------- prep kernels ----------------

// out[n][k] = (f16) in[k][n]   (tiled transpose + convert)
__global__ void transpose_cvt(const float* __restrict__ in, f16* __restrict__ out,
                              int K, int N) {
  __shared__ float t[32][33];
  int n0 = blockIdx.x * 32, k0 = blockIdx.y * 32;
  int tx = threadIdx.x, ty = threadIdx.y; // (32,8)
#pragma unroll
  for (int i = 0; i < 32; i += 8)
    t[ty + i][tx] = in[(size_t)(k0 + ty + i) * N + n0 + tx];
  __syncthreads();
#pragma unroll
  for (int i = 0; i < 32; i += 8)
    out[(size_t)(n0 + ty + i) * K + k0 + tx] = (f16)t[tx][ty + i];
}

// Hp[(k8*Hd + j)*8 + i] = (f16) H[(k8*8+i)*Hd + j]  -> 16B per (k8,j), coalesced
__global__ void pack_H(const float* __restrict__ Hm, f16* __restrict__ Hp) {
  int j = blockIdx.x * blockDim.x + threadIdx.x;
  int k8 = blockIdx.y;
  f16x8 v;
#pragma unroll
  for (int i = 0; i < 8; ++i) v[i] = (f16)Hm[(size_t)(k8 * 8 + i) * Hd + j];
  *(f16x8*)(Hp + ((size_t)k8 * Hd + j) * 8) = v;
}

// xg[m][e] = (f16) emb[tok[m]][e], m = t*B+b, tokens are [B][T]
__global__ void gather_emb(const int* __restrict__ tok, const float* __restrict__ emb,
                           f16* __restrict__ xg) {
  int m = blockIdx.x;
  int b = m % Bb, t = m / Bb;
  int token = tok[b * Tt + t];
  const float* src = emb + (size_t)token * Ee;
  f16* dst = xg + (size_t)m * Ee;
  int e = threadIdx.x * 4; // 256 threads * 4 = 1024 = Ee
  float4 v = *(const float4*)(src + e);
  f16x4 o = {(f16)v.x, (f16)v.y, (f16)v.z, (f16)v.w};
  *(f16x4*)(dst + e) = o;
}

// ---------------- GEMM: C[M][N] f32 = A[M][K]f16 @ Bt[N][K]f16^T + bias ----------------
// 128x128 block tile, BK=32, 4 waves (2x2), wave tile 64x64 = 4x4 frags of 16x16x32.
__global__ __launch_bounds__(256) void gemm_f16(
    const f16* __restrict__ A, const f16* __restrict__ Bt,
    const float* __restrict__ bias, float* __restrict__ C, int M, int N, int K) {
  __shared__ __align__(16) f16 As[128 * 32];
  __shared__ __align__(16) f16 Bs[128 * 32];

  const int ntiles = N >> 7;
  const int tm = blockIdx.x / ntiles, tn = blockIdx.x % ntiles;
  const int tid = threadIdx.x;
  const int lane = tid & 63, wid = tid >> 6;
  const int wm = wid >> 1, wn = wid & 1;

  // staging map: thread covers (row = tid/4, kblock = tid%4) == LDS byte tid*16
  const int srow = tid >> 2, skb = tid & 3;
  const f16* gA0 = A + (size_t)(tm * 128 + srow) * K + skb * 8;
  const f16* gA1 = gA0 + (size_t)64 * K;
  const f16* gB0 = Bt + (size_t)(tn * 128 + srow) * K + skb * 8;
  const f16* gB1 = gB0 + (size_t)64 * K;
  f16* lA0 = As + wid * 512;        // bytes wid*1024
  f16* lA1 = As + 2048 + wid * 512; // bytes 4096 + wid*1024
  f16* lB0 = Bs + wid * 512;
  f16* lB1 = Bs + 2048 + wid * 512;

  f32x4 acc[4][4] = {};

  const int r = lane & 15, kb = lane >> 4;
  for (int kc = 0; kc < K; kc += 32) {
    __syncthreads(); // previous iter's LDS reads done
    GLOAD16(gA0 + kc, lA0);
    GLOAD16(gA1 + kc, lA1);
    GLOAD16(gB0 + kc, lB0);
    GLOAD16(gB1 + kc, lB1);
    __syncthreads(); // vmcnt(0) drained by compiler before barrier

    f16x8 af[4], bf[4];
#pragma unroll
    for (int i = 0; i < 4; ++i) {
      af[i] = *(const f16x8*)(As + (wm * 64 + i * 16 + r) * 32 + kb * 8);
      bf[i] = *(const f16x8*)(Bs + (wn * 64 + i * 16 + r) * 32 + kb * 8);
    }
#pragma unroll
    for (int i = 0; i < 4; ++i)
#pragma unroll
      for (int j = 0; j < 4; ++j)
        acc[i][j] = __builtin_amdgcn_mfma_f32_16x16x32_f16(af[i], bf[j], acc[i][j], 0, 0, 0);
  }

  // epilogue: D frag layout col=lane&15, row=(lane>>4)*4+reg (m89-verified)
  const int col0 = tn * 128 + wn * 64, row0 = tm * 128 + wm * 64;
#pragma unroll
  for (int i = 0; i < 4; ++i)
#pragma unroll
    for (int j = 0; j < 4; ++j) {
      int c = col0 + j * 16 + (lane & 15);
      int rbase = row0 + i * 16 + (lane >> 4) * 4;
      float bv = bias ? bias[c] : 0.f;
#pragma unroll
      for (int rr = 0; rr < 4; ++rr)
        C[(size_t)(rbase + rr) * N + c] = acc[i][j][rr] + bv;
    }
}

// ---------------- recurrence ----------------
__device__ __forceinline__ float dot8(f16x8 a, f16x8 b, float c) {
#if __has_builtin(__builtin_amdgcn_fdot2)
  c = __builtin_amdgcn_fdot2(__builtin_shufflevector(a, a, 0, 1),
                             __builtin_shufflevector(b, b, 0, 1), c, false);
  c = __builtin_amdgcn_fdot2(__builtin_shufflevector(a, a, 2, 3),
                             __builtin_shufflevector(b, b, 2, 3), c, false);
  c = __builtin_amdgcn_fdot2(__builtin_shufflevector(a, a, 4, 5),
                             __builtin_shufflevector(b, b, 4, 5), c, false);
  c = __builtin_amdgcn_fdot2(__builtin_shufflevector(a, a, 6, 7),
                             __builtin_shufflevector(b, b, 6, 7), c, false);
#else
#pragma unroll
  for (int i = 0; i < 8; ++i) c += (float)a[i] * (float)b[i];
#endif
  return c;
}

// one block per batch row b; thread j = output column; h broadcast from LDS
__global__ __launch_bounds__(1024) void recurrence(
    const float* __restrict__ xI, const float* __restrict__ h0,
    const f16* __restrict__ Hp, f16* __restrict__ hs, float* __restrict__ hN) {
  __shared__ __align__(16) f16 hl[Hd];
  const int b = blockIdx.x, j = threadIdx.x;
  float h = h0[(size_t)b * Hd + j];
  hl[j] = (f16)h;
  __syncthreads();
  for (int t = 0; t < Tt; ++t) {
    float acc = xI[(size_t)(t * Bb + b) * Hd + j]; // includes b1
#pragma unroll 4
    for (int k8 = 0; k8 < Hd / 8; ++k8) {
      f16x8 hv = *(const f16x8*)(hl + k8 * 8);                    // LDS broadcast
      f16x8 wv = *(const f16x8*)(Hp + ((size_t)k8 * Hd + j) * 8); // coalesced 16B/lane
      acc = dot8(hv, wv, acc);
    }
    float hn = 1.f / (1.f + __expf(-acc));
    hs[(size_t)(t * Bb + b) * Hd + j] = (f16)hn;
    __syncthreads(); // all reads of hl done
    hl[j] = (f16)hn;
    h = hn;
    __syncthreads();
  }
  hN[(size_t)b * Hd + j] = h;
}

// ---------------- launcher ----------------
extern "C" void kernel_launch(void* const* d_in, const int* in_sizes, int n_in,
                              void* d_out, int out_size, void* d_ws, size_t ws_size,
                              hipStream_t stream) {
  const int* input_x = (const int*)d_in[0];
  const float* h0 = (const float*)d_in[1];
  const float* emb = (const float*)d_in[2];
  const float* Hm = (const float*)d_in[3];
  const float* Im = (const float*)d_in[4];
  const float* b1 = (const float*)d_in[5];
  const float* Um = (const float*)d_in[6];
  const float* b2 = (const float*)d_in[7];
  float* out = (float*)d_out;

  char* ws = (char*)d_ws;
  size_t off = 0;
  auto alloc = [&](size_t bytes) { void* p = ws + off; off = (off + bytes + 255) & ~(size_t)255; return p; };
  f16* Ut = (f16*)alloc((size_t)Vv * Hd * 2);  // U^T f16 [V][Hd]
  f16* It = (f16*)alloc((size_t)Hd * Ee * 2);  // I^T f16 [Hd][E]
  f16* Hp = (f16*)alloc((size_t)Hd * Hd * 2);  // packed H
  f16* xg = (f16*)alloc((size_t)Mm * Ee * 2);  // gathered emb f16
  float* xI = (float*)alloc((size_t)Mm * Hd * 4);
  f16* hs = (f16*)alloc((size_t)Mm * Hd * 2);
  (void)ws_size; (void)in_sizes; (void)n_in; (void)out_size;

  // prep
  transpose_cvt<<<dim3(Vv / 32, Hd / 32), dim3(32, 8), 0, stream>>>(Um, Ut, Hd, Vv);
  transpose_cvt<<<dim3(Hd / 32, Ee / 32), dim3(32, 8), 0, stream>>>(Im, It, Ee, Hd);
  pack_H<<<dim3(Hd / 256, Hd / 8), 256, 0, stream>>>(Hm, Hp);
  gather_emb<<<Mm, 256, 0, stream>>>(input_x, emb, xg);

  // xI = xg @ I + b1   (M=2048, N=1024, K=1024)
  gemm_f16<<<(Mm / 128) * (Hd / 128), 256, 0, stream>>>(xg, It, b1, xI, Mm, Hd, Ee);

  // recurrence -> hs (f16) and final state -> tail of d_out
  recurrence<<<Bb, Hd, 0, stream>>>(xI, h0, Hp, hs, out + (size_t)Mm * Vv);

  // logits = hs @ U + b2   (M=2048, N=32000, K=1024) -> d_out
  gemm_f16<<<(Mm / 128) * (Vv / 128), 256, 0, stream>>>(hs, Ut, b2, out, Mm, Vv, Hd);
}

// Round 2
// 887.347 us; speedup vs baseline: 1.4026x; 1.4026x over previous
//
#include <hip/hip_runtime.h>

// RNNLM: logits[T,B,V] = (scan_t sigmoid(h@H + emb[x]@I + b1)) @ U + b2 ; plus final h.
// V=32000 E=1024 Hd=1024 T=64 B=32.
// R1 change: recurrence rebuilt as cooperative MFMA kernel (64 blocks x 4 waves),
// H held in VGPR B-fragments (loaded once), grid barrier per timestep via
// device-scope atomic counter + agent fences. Kills the per-CU L2-BW bound
// (was: 32 blocks x 64 steps x 2MB H re-read = 958us).

typedef _Float16 f16;
typedef f16 f16x4 __attribute__((ext_vector_type(4)));
typedef f16 f16x8 __attribute__((ext_vector_type(8)));
typedef float f32x4 __attribute__((ext_vector_type(4)));

static constexpr int Vv = 32000, Ee = 1024, Hd = 1024, Tt = 64, Bb = 32;
static constexpr int Mm = Tt * Bb; // 2048 rows (t*B+b)

// async global->LDS, 16B per lane; LDS dest = wave-uniform base + lane*16
#define GLOAD16(g, l)                                                          \
  __builtin_amdgcn_global_load_lds(                                            \
      (const __attribute__((address_space(1))) void*)(g),                      \
      (__attribute__((address_space(3))) void*)(l), 16, 0, 0)

// ---------------- prep kernels ----------------

// out[n][k] = (f16) in[k][n]   (tiled transpose + convert)
__global__ void transpose_cvt(const float* __restrict__ in, f16* __restrict__ out,
                              int K, int N) {
  __shared__ float t[32][33];
  int n0 = blockIdx.x * 32, k0 = blockIdx.y * 32;
  int tx = threadIdx.x, ty = threadIdx.y; // (32,8)
#pragma unroll
  for (int i = 0; i < 32; i += 8)
    t[ty + i][tx] = in[(size_t)(k0 + ty + i) * N + n0 + tx];
  __syncthreads();
#pragma unroll
  for (int i = 0; i < 32; i += 8)
    out[(size_t)(n0 + ty + i) * K + k0 + tx] = (f16)t[tx][ty + i];
}

// xg[m][e] = (f16) emb[tok[m]][e], m = t*B+b, tokens are [B][T]
__global__ void gather_emb(const int* __restrict__ tok, const float* __restrict__ emb,
                           f16* __restrict__ xg) {
  int m = blockIdx.x;
  int b = m % Bb, t = m / Bb;
  int token = tok[b * Tt + t];
  const float* src = emb + (size_t)token * Ee;
  f16* dst = xg + (size_t)m * Ee;
  int e = threadIdx.x * 4; // 256 threads * 4 = 1024 = Ee
  float4 v = *(const float4*)(src + e);
  f16x4 o = {(f16)v.x, (f16)v.y, (f16)v.z, (f16)v.w};
  *(f16x4*)(dst + e) = o;
}

__global__ void cvt_h0(const float* __restrict__ h0, f16* __restrict__ h0f) {
  int i = blockIdx.x * 256 + threadIdx.x;
  h0f[i] = (f16)h0[i];
}

// ---------------- GEMM: C[M][N] f32 = A[M][K]f16 @ Bt[N][K]f16^T + bias ----------------
// 128x128 block tile, BK=32, 4 waves (2x2), wave tile 64x64 = 4x4 frags of 16x16x32.
__global__ __launch_bounds__(256) void gemm_f16(
    const f16* __restrict__ A, const f16* __restrict__ Bt,
    const float* __restrict__ bias, float* __restrict__ C, int M, int N, int K) {
  __shared__ __align__(16) f16 As[128 * 32];
  __shared__ __align__(16) f16 Bs[128 * 32];

  const int ntiles = N >> 7;
  const int tm = blockIdx.x / ntiles, tn = blockIdx.x % ntiles;
  const int tid = threadIdx.x;
  const int lane = tid & 63, wid = tid >> 6;
  const int wm = wid >> 1, wn = wid & 1;

  // staging map: thread covers (row = tid/4, kblock = tid%4) == LDS byte tid*16
  const int srow = tid >> 2, skb = tid & 3;
  const f16* gA0 = A + (size_t)(tm * 128 + srow) * K + skb * 8;
  const f16* gA1 = gA0 + (size_t)64 * K;
  const f16* gB0 = Bt + (size_t)(tn * 128 + srow) * K + skb * 8;
  const f16* gB1 = gB0 + (size_t)64 * K;
  f16* lA0 = As + wid * 512;        // bytes wid*1024
  f16* lA1 = As + 2048 + wid * 512; // bytes 4096 + wid*1024
  f16* lB0 = Bs + wid * 512;
  f16* lB1 = Bs + 2048 + wid * 512;

  f32x4 acc[4][4] = {};

  const int r = lane & 15, kb = lane >> 4;
  for (int kc = 0; kc < K; kc += 32) {
    __syncthreads(); // previous iter's LDS reads done
    GLOAD16(gA0 + kc, lA0);
    GLOAD16(gA1 + kc, lA1);
    GLOAD16(gB0 + kc, lB0);
    GLOAD16(gB1 + kc, lB1);
    __syncthreads(); // vmcnt(0) drained by compiler before barrier

    f16x8 af[4], bf[4];
#pragma unroll
    for (int i = 0; i < 4; ++i) {
      af[i] = *(const f16x8*)(As + (wm * 64 + i * 16 + r) * 32 + kb * 8);
      bf[i] = *(const f16x8*)(Bs + (wn * 64 + i * 16 + r) * 32 + kb * 8);
    }
#pragma unroll
    for (int i = 0; i < 4; ++i)
#pragma unroll
      for (int j = 0; j < 4; ++j)
        acc[i][j] = __builtin_amdgcn_mfma_f32_16x16x32_f16(af[i], bf[j], acc[i][j], 0, 0, 0);
  }

  // epilogue: D frag layout col=lane&15, row=(lane>>4)*4+reg (bench-verified R0)
  const int col0 = tn * 128 + wn * 64, row0 = tm * 128 + wm * 64;
#pragma unroll
  for (int i = 0; i < 4; ++i)
#pragma unroll
    for (int j = 0; j < 4; ++j) {
      int c = col0 + j * 16 + (lane & 15);
      int rbase = row0 + i * 16 + (lane >> 4) * 4;
      float bv = bias ? bias[c] : 0.f;
#pragma unroll
      for (int rr = 0; rr < 4; ++rr)
        C[(size_t)(rbase + rr) * N + c] = acc[i][j][rr] + bv;
    }
}

// ---------------- cooperative MFMA recurrence ----------------
// 64 blocks x 256 threads. Block bn owns output cols [bn*16, bn*16+16).
// Wave w (0..3) owns K-slice [w*256, w*256+256), holds its H-slice as 8 MFMA
// B-fragments in VGPRs (loaded once). Per step: load A-frags of h_{t-1} from
// global, 16 MFMA, LDS-reduce 4 K-partials, +xI, sigmoid, store h_t, grid sync.
__global__ __launch_bounds__(256) void recurrence_mfma(
    const float* __restrict__ Hf,  // H f32 [Hd][Hd] (k-major rows)
    const float* __restrict__ xI,  // [T*B][Hd], includes b1
    const f16* __restrict__ h0f,   // [B][Hd] f16
    f16* __restrict__ hs,          // [T*B][Hd] f16
    float* __restrict__ hN,        // [B][Hd] f32 (final state -> d_out tail)
    int* __restrict__ cnt) {
  __shared__ float red[4][512];
  const int tid = threadIdx.x;
  const int lane = tid & 63, w = tid >> 6;
  const int bn = blockIdx.x;
  const int nb = gridDim.x;
  const int r = lane & 15, kb = lane >> 4;
  const int colg = bn * 16 + r;

  // one-time B-frags: bH[ks][j] = H[w*256 + ks*32 + kb*8 + j][colg]
  f16x8 bH[8];
#pragma unroll
  for (int ks = 0; ks < 8; ++ks) {
    f16x8 v;
#pragma unroll
    for (int j = 0; j < 8; ++j)
      v[j] = (f16)Hf[(size_t)(w * 256 + ks * 32 + kb * 8 + j) * Hd + colg];
    bH[ks] = v;
  }

  for (int t = 0; t < Tt; ++t) {
    const f16* hp = t ? hs + (size_t)(t - 1) * Bb * Hd : h0f;
    f32x4 acc[2] = {};
#pragma unroll
    for (int mt = 0; mt < 2; ++mt) {
      f16x8 af[8];
#pragma unroll
      for (int ks = 0; ks < 8; ++ks)
        af[ks] = *(const f16x8*)(hp + (size_t)(mt * 16 + r) * Hd + w * 256 + ks * 32 + kb * 8);
#pragma unroll
      for (int ks = 0; ks < 8; ++ks)
        acc[mt] = __builtin_amdgcn_mfma_f32_16x16x32_f16(af[ks], bH[ks], acc[mt], 0, 0, 0);
    }
    // D-frag: reg q holds D[row=kb*4+q][col=r] of m-tile mt
#pragma unroll
    for (int mt = 0; mt < 2; ++mt)
#pragma unroll
      for (int q = 0; q < 4; ++q)
        red[w][mt * 256 + (kb * 4 + q) * 16 + r] = acc[mt][q];
    __syncthreads();
#pragma unroll
    for (int o = tid; o < 512; o += 256) {
      int b = o >> 4, cl = o & 15;
      float v = red[0][o] + red[1][o] + red[2][o] + red[3][o] +
                xI[(size_t)(t * Bb + b) * Hd + bn * 16 + cl];
      float s = 1.f / (1.f + __expf(-v));
      hs[(size_t)(t * Bb + b) * Hd + bn * 16 + cl] = (f16)s;
      if (t == Tt - 1) hN[(size_t)b * Hd + bn * 16 + cl] = s;
    }
    // ---- grid barrier (device-scope; per-XCD L2s are non-coherent) ----
    __syncthreads(); // all red reads + hs stores issued (vmcnt drained at barrier)
    if (tid == 0) {
      __builtin_amdgcn_fence(__ATOMIC_RELEASE, "agent"); // flush this XCD's L2
      __hip_atomic_fetch_add(cnt, 1, __ATOMIC_RELAXED, __HIP_MEMORY_SCOPE_AGENT);
      const int target = (t + 1) * nb;
      while (__hip_atomic_load(cnt, __ATOMIC_RELAXED, __HIP_MEMORY_SCOPE_AGENT) < target)
        __builtin_amdgcn_s_sleep(1);
    }
    __syncthreads();
    __builtin_amdgcn_fence(__ATOMIC_ACQUIRE, "agent"); // invalidate stale L1/L2
  }
}

// ---------------- launcher ----------------
extern "C" void kernel_launch(void* const* d_in, const int* in_sizes, int n_in,
                              void* d_out, int out_size, void* d_ws, size_t ws_size,
                              hipStream_t stream) {
  const int* input_x = (const int*)d_in[0];
  const float* h0 = (const float*)d_in[1];
  const float* emb = (const float*)d_in[2];
  const float* Hm = (const float*)d_in[3];
  const float* Im = (const float*)d_in[4];
  const float* b1 = (const float*)d_in[5];
  const float* Um = (const float*)d_in[6];
  const float* b2 = (const float*)d_in[7];
  float* out = (float*)d_out;

  char* ws = (char*)d_ws;
  size_t off = 0;
  auto alloc = [&](size_t bytes) { void* p = ws + off; off = (off + bytes + 255) & ~(size_t)255; return p; };
  f16* Ut = (f16*)alloc((size_t)Vv * Hd * 2);  // U^T f16 [V][Hd]
  f16* It = (f16*)alloc((size_t)Hd * Ee * 2);  // I^T f16 [Hd][E]
  f16* xg = (f16*)alloc((size_t)Mm * Ee * 2);  // gathered emb f16
  float* xI = (float*)alloc((size_t)Mm * Hd * 4);
  f16* hs = (f16*)alloc((size_t)Mm * Hd * 2);
  f16* h0f = (f16*)alloc((size_t)Bb * Hd * 2);
  int* cnt = (int*)alloc(256);
  (void)ws_size; (void)in_sizes; (void)n_in; (void)out_size;

  hipMemsetAsync(cnt, 0, sizeof(int), stream); // grid-barrier counter = 0 (in-graph)

  // prep
  transpose_cvt<<<dim3(Vv / 32, Hd / 32), dim3(32, 8), 0, stream>>>(Um, Ut, Hd, Vv);
  transpose_cvt<<<dim3(Hd / 32, Ee / 32), dim3(32, 8), 0, stream>>>(Im, It, Ee, Hd);
  gather_emb<<<Mm, 256, 0, stream>>>(input_x, emb, xg);
  cvt_h0<<<(Bb * Hd) / 256, 256, 0, stream>>>(h0, h0f);

  // xI = xg @ I + b1   (M=2048, N=1024, K=1024)
  gemm_f16<<<(Mm / 128) * (Hd / 128), 256, 0, stream>>>(xg, It, b1, xI, Mm, Hd, Ee);

  // recurrence -> hs (f16) and final state -> tail of d_out
  recurrence_mfma<<<64, 256, 0, stream>>>(Hm, xI, h0f, hs, out + (size_t)Mm * Vv, cnt);

  // logits = hs @ U + b2   (M=2048, N=32000, K=1024) -> d_out
  gemm_f16<<<(Mm / 128) * (Vv / 128), 256, 0, stream>>>(hs, Ut, b2, out, Mm, Vv, Hd);
}

// Round 3
// 605.216 us; speedup vs baseline: 2.0564x; 1.4662x over previous
//
#include <hip/hip_runtime.h>

// RNNLM: logits[T,B,V] = (scan_t sigmoid(h@H + emb[x]@I + b1)) @ U + b2 ; plus final h.
// V=32000 E=1024 Hd=1024 T=64 B=32.
// R2 change: recurrence grid-sync without agent fences. R2's 9.1us/step was
// buffer_wbl2 + buffer_inv (full L2 writeback/invalidate) per block per step.
// Now: h_t stores are per-access coherent (__hip_atomic_store u32, RELAXED/AGENT
// -> sc1 write-through past the XCD-private L2 into L3); pre-signal
// __syncthreads drains vmcnt(0) block-wide before the arrival atomic; consumer
// h reads stay plain f16x8 (first-touch per address within the kernel, fill
// from L3 which holds the only copy). Barrier = 1 atomic add per block +
// all-wave spin on the counter. No fences anywhere.

typedef _Float16 f16;
typedef f16 f16x4 __attribute__((ext_vector_type(4)));
typedef f16 f16x8 __attribute__((ext_vector_type(8)));
typedef float f32x4 __attribute__((ext_vector_type(4)));

static constexpr int Vv = 32000, Ee = 1024, Hd = 1024, Tt = 64, Bb = 32;
static constexpr int Mm = Tt * Bb; // 2048 rows (t*B+b)

// async global->LDS, 16B per lane; LDS dest = wave-uniform base + lane*16
#define GLOAD16(g, l)                                                          \
  __builtin_amdgcn_global_load_lds(                                            \
      (const __attribute__((address_space(1))) void*)(g),                      \
      (__attribute__((address_space(3))) void*)(l), 16, 0, 0)

// ---------------- prep kernels ----------------

// out[n][k] = (f16) in[k][n]   (tiled transpose + convert)
__global__ void transpose_cvt(const float* __restrict__ in, f16* __restrict__ out,
                              int K, int N) {
  __shared__ float t[32][33];
  int n0 = blockIdx.x * 32, k0 = blockIdx.y * 32;
  int tx = threadIdx.x, ty = threadIdx.y; // (32,8)
#pragma unroll
  for (int i = 0; i < 32; i += 8)
    t[ty + i][tx] = in[(size_t)(k0 + ty + i) * N + n0 + tx];
  __syncthreads();
#pragma unroll
  for (int i = 0; i < 32; i += 8)
    out[(size_t)(n0 + ty + i) * K + k0 + tx] = (f16)t[tx][ty + i];
}

// xg[m][e] = (f16) emb[tok[m]][e], m = t*B+b, tokens are [B][T]
__global__ void gather_emb(const int* __restrict__ tok, const float* __restrict__ emb,
                           f16* __restrict__ xg) {
  int m = blockIdx.x;
  int b = m % Bb, t = m / Bb;
  int token = tok[b * Tt + t];
  const float* src = emb + (size_t)token * Ee;
  f16* dst = xg + (size_t)m * Ee;
  int e = threadIdx.x * 4; // 256 threads * 4 = 1024 = Ee
  float4 v = *(const float4*)(src + e);
  f16x4 o = {(f16)v.x, (f16)v.y, (f16)v.z, (f16)v.w};
  *(f16x4*)(dst + e) = o;
}

__global__ void cvt_h0(const float* __restrict__ h0, f16* __restrict__ h0f) {
  int i = blockIdx.x * 256 + threadIdx.x;
  h0f[i] = (f16)h0[i];
}

// ---------------- GEMM: C[M][N] f32 = A[M][K]f16 @ Bt[N][K]f16^T + bias ----------------
// 128x128 block tile, BK=32, 4 waves (2x2), wave tile 64x64 = 4x4 frags of 16x16x32.
__global__ __launch_bounds__(256) void gemm_f16(
    const f16* __restrict__ A, const f16* __restrict__ Bt,
    const float* __restrict__ bias, float* __restrict__ C, int M, int N, int K) {
  __shared__ __align__(16) f16 As[128 * 32];
  __shared__ __align__(16) f16 Bs[128 * 32];

  const int ntiles = N >> 7;
  const int tm = blockIdx.x / ntiles, tn = blockIdx.x % ntiles;
  const int tid = threadIdx.x;
  const int lane = tid & 63, wid = tid >> 6;
  const int wm = wid >> 1, wn = wid & 1;

  // staging map: thread covers (row = tid/4, kblock = tid%4) == LDS byte tid*16
  const int srow = tid >> 2, skb = tid & 3;
  const f16* gA0 = A + (size_t)(tm * 128 + srow) * K + skb * 8;
  const f16* gA1 = gA0 + (size_t)64 * K;
  const f16* gB0 = Bt + (size_t)(tn * 128 + srow) * K + skb * 8;
  const f16* gB1 = gB0 + (size_t)64 * K;
  f16* lA0 = As + wid * 512;        // bytes wid*1024
  f16* lA1 = As + 2048 + wid * 512; // bytes 4096 + wid*1024
  f16* lB0 = Bs + wid * 512;
  f16* lB1 = Bs + 2048 + wid * 512;

  f32x4 acc[4][4] = {};

  const int r = lane & 15, kb = lane >> 4;
  for (int kc = 0; kc < K; kc += 32) {
    __syncthreads(); // previous iter's LDS reads done
    GLOAD16(gA0 + kc, lA0);
    GLOAD16(gA1 + kc, lA1);
    GLOAD16(gB0 + kc, lB0);
    GLOAD16(gB1 + kc, lB1);
    __syncthreads(); // vmcnt(0) drained by compiler before barrier

    f16x8 af[4], bf[4];
#pragma unroll
    for (int i = 0; i < 4; ++i) {
      af[i] = *(const f16x8*)(As + (wm * 64 + i * 16 + r) * 32 + kb * 8);
      bf[i] = *(const f16x8*)(Bs + (wn * 64 + i * 16 + r) * 32 + kb * 8);
    }
#pragma unroll
    for (int i = 0; i < 4; ++i)
#pragma unroll
      for (int j = 0; j < 4; ++j)
        acc[i][j] = __builtin_amdgcn_mfma_f32_16x16x32_f16(af[i], bf[j], acc[i][j], 0, 0, 0);
  }

  // epilogue: D frag layout col=lane&15, row=(lane>>4)*4+reg (bench-verified R0)
  const int col0 = tn * 128 + wn * 64, row0 = tm * 128 + wm * 64;
#pragma unroll
  for (int i = 0; i < 4; ++i)
#pragma unroll
    for (int j = 0; j < 4; ++j) {
      int c = col0 + j * 16 + (lane & 15);
      int rbase = row0 + i * 16 + (lane >> 4) * 4;
      float bv = bias ? bias[c] : 0.f;
#pragma unroll
      for (int rr = 0; rr < 4; ++rr)
        C[(size_t)(rbase + rr) * N + c] = acc[i][j][rr] + bv;
    }
}

// ---------------- cooperative MFMA recurrence ----------------
// 64 blocks x 256 threads. Block bn owns output cols [bn*16, bn*16+16).
// Wave w (0..3) owns K-slice [w*256, ...), holds its H-slice as 8 MFMA
// B-fragments in VGPRs (loaded once). Per step: plain f16x8 loads of h_{t-1}
// (first-touch, fills from L3), 16 MFMA, LDS-reduce, sigmoid, coherent packed
// store of h_t, drain via __syncthreads, 1 arrival atomic, all-wave spin.
__global__ __launch_bounds__(256) void recurrence_mfma(
    const float* __restrict__ Hf,  // H f32 [Hd][Hd] (k-major rows)
    const float* __restrict__ xI,  // [T*B][Hd], includes b1
    const f16* __restrict__ h0f,   // [B][Hd] f16
    f16* __restrict__ hs,          // [T*B][Hd] f16
    float* __restrict__ hN,        // [B][Hd] f32 (final state -> d_out tail)
    int* __restrict__ cnt) {
  __shared__ float red[4][512];
  const int tid = threadIdx.x;
  const int lane = tid & 63, w = tid >> 6;
  const int bn = blockIdx.x;
  const int nb = gridDim.x;
  const int r = lane & 15, kb = lane >> 4;
  const int colg = bn * 16 + r;

  // one-time B-frags: bH[ks][j] = H[w*256 + ks*32 + kb*8 + j][colg]
  f16x8 bH[8];
#pragma unroll
  for (int ks = 0; ks < 8; ++ks) {
    f16x8 v;
#pragma unroll
    for (int j = 0; j < 8; ++j)
      v[j] = (f16)Hf[(size_t)(w * 256 + ks * 32 + kb * 8 + j) * Hd + colg];
    bH[ks] = v;
  }

  // epilogue mapping: thread -> (batch eb, col-pair ecp); 32*8 = 256 threads
  const int eb = tid >> 3, ecp = tid & 7;

  for (int t = 0; t < Tt; ++t) {
    const f16* hp = t ? hs + (size_t)(t - 1) * Bb * Hd : h0f;
    f32x4 acc[2] = {};
#pragma unroll
    for (int mt = 0; mt < 2; ++mt) {
      f16x8 af[8];
#pragma unroll
      for (int ks = 0; ks < 8; ++ks)
        af[ks] = *(const f16x8*)(hp + (size_t)(mt * 16 + r) * Hd + w * 256 + ks * 32 + kb * 8);
#pragma unroll
      for (int ks = 0; ks < 8; ++ks)
        acc[mt] = __builtin_amdgcn_mfma_f32_16x16x32_f16(af[ks], bH[ks], acc[mt], 0, 0, 0);
    }
    // D-frag: reg q holds D[row=kb*4+q + mt*16][col=r]; red[w] is [32 b][16 col]
#pragma unroll
    for (int mt = 0; mt < 2; ++mt)
#pragma unroll
      for (int q = 0; q < 4; ++q)
        red[w][mt * 256 + (kb * 4 + q) * 16 + r] = acc[mt][q];
    __syncthreads();

    // epilogue: 2 cols per thread, packed coherent store (sc1, bypasses XCD L2)
    {
      const float2 r0 = *(const float2*)&red[0][eb * 16 + 2 * ecp];
      const float2 r1 = *(const float2*)&red[1][eb * 16 + 2 * ecp];
      const float2 r2 = *(const float2*)&red[2][eb * 16 + 2 * ecp];
      const float2 r3 = *(const float2*)&red[3][eb * 16 + 2 * ecp];
      const float2 xv = *(const float2*)(xI + (size_t)(t * Bb + eb) * Hd + bn * 16 + 2 * ecp);
      float v0 = r0.x + r1.x + r2.x + r3.x + xv.x;
      float v1 = r0.y + r1.y + r2.y + r3.y + xv.y;
      float s0 = 1.f / (1.f + __expf(-v0));
      float s1 = 1.f / (1.f + __expf(-v1));
      union { f16 h[2]; unsigned u; } pk;
      pk.h[0] = (f16)s0;
      pk.h[1] = (f16)s1;
      unsigned* dst = (unsigned*)(hs + (size_t)(t * Bb + eb) * Hd + bn * 16 + 2 * ecp);
      __hip_atomic_store(dst, pk.u, __ATOMIC_RELAXED, __HIP_MEMORY_SCOPE_AGENT);
      if (t == Tt - 1)
        *(float2*)(hN + (size_t)eb * Hd + bn * 16 + 2 * ecp) = make_float2(s0, s1);
    }

    // ---- grid barrier, fence-free ----
    __syncthreads(); // red reads done; vmcnt(0) drained block-wide (incl. coherent stores)
    if (tid == 0)
      (void)__hip_atomic_fetch_add(cnt, 1, __ATOMIC_RELAXED, __HIP_MEMORY_SCOPE_AGENT);
    const int target = (t + 1) * nb;
    while (__hip_atomic_load(cnt, __ATOMIC_RELAXED, __HIP_MEMORY_SCOPE_AGENT) < target)
      __builtin_amdgcn_s_sleep(1); // one coalesced coherent load per wave per poll
  }
}

// ---------------- launcher ----------------
extern "C" void kernel_launch(void* const* d_in, const int* in_sizes, int n_in,
                              void* d_out, int out_size, void* d_ws, size_t ws_size,
                              hipStream_t stream) {
  const int* input_x = (const int*)d_in[0];
  const float* h0 = (const float*)d_in[1];
  const float* emb = (const float*)d_in[2];
  const float* Hm = (const float*)d_in[3];
  const float* Im = (const float*)d_in[4];
  const float* b1 = (const float*)d_in[5];
  const float* Um = (const float*)d_in[6];
  const float* b2 = (const float*)d_in[7];
  float* out = (float*)d_out;

  char* ws = (char*)d_ws;
  size_t off = 0;
  auto alloc = [&](size_t bytes) { void* p = ws + off; off = (off + bytes + 255) & ~(size_t)255; return p; };
  f16* Ut = (f16*)alloc((size_t)Vv * Hd * 2);  // U^T f16 [V][Hd]
  f16* It = (f16*)alloc((size_t)Hd * Ee * 2);  // I^T f16 [Hd][E]
  f16* xg = (f16*)alloc((size_t)Mm * Ee * 2);  // gathered emb f16
  float* xI = (float*)alloc((size_t)Mm * Hd * 4);
  f16* hs = (f16*)alloc((size_t)Mm * Hd * 2);
  f16* h0f = (f16*)alloc((size_t)Bb * Hd * 2);
  int* cnt = (int*)alloc(256);
  (void)ws_size; (void)in_sizes; (void)n_in; (void)out_size;

  hipMemsetAsync(cnt, 0, sizeof(int), stream); // grid-barrier counter = 0 (in-graph)

  // prep
  transpose_cvt<<<dim3(Vv / 32, Hd / 32), dim3(32, 8), 0, stream>>>(Um, Ut, Hd, Vv);
  transpose_cvt<<<dim3(Hd / 32, Ee / 32), dim3(32, 8), 0, stream>>>(Im, It, Ee, Hd);
  gather_emb<<<Mm, 256, 0, stream>>>(input_x, emb, xg);
  cvt_h0<<<(Bb * Hd) / 256, 256, 0, stream>>>(h0, h0f);

  // xI = xg @ I + b1   (M=2048, N=1024, K=1024)
  gemm_f16<<<(Mm / 128) * (Hd / 128), 256, 0, stream>>>(xg, It, b1, xI, Mm, Hd, Ee);

  // recurrence -> hs (f16) and final state -> tail of d_out
  recurrence_mfma<<<64, 256, 0, stream>>>(Hm, xI, h0f, hs, out + (size_t)Mm * Vv, cnt);

  // logits = hs @ U + b2   (M=2048, N=32000, K=1024) -> d_out
  gemm_f16<<<(Mm / 128) * (Vv / 128), 256, 0, stream>>>(hs, Ut, b2, out, Mm, Vv, Hd);
}